// Round 12
// baseline (287.522 us; speedup 1.0000x reference)
//
#include <hip/hip_runtime.h>
#include <hip/hip_bf16.h>
#include <hip/hip_fp16.h>

typedef _Float16 v8h __attribute__((ext_vector_type(8)));
typedef float v4f __attribute__((ext_vector_type(4)));

// ---------------- K_A: per-block dst-bucket histogram (LDS) + W-swizzle (fused) ----------------
__global__ __launch_bounds__(256) void hist_wswz(const int* __restrict__ dst,
                                                 int* __restrict__ histT, int E,
                                                 int histBlocks,
                                                 const float* __restrict__ W1,
                                                 const float* __restrict__ W2,
                                                 const float* __restrict__ W3,
                                                 __half* __restrict__ wfrag) {
    int tid = threadIdx.x;
    if (blockIdx.x >= histBlocks) {
        int o = (blockIdx.x - histBlocks) * 256 + tid;
        int w = o >> 14, r = o & 16383;
        const float* Ws = (w >= 3) ? W3 : ((w == 2) ? W2 : W1);
        float v = Ws[r];
        __half h;
        if (w == 1) {
            __half hv = __float2half_rn(v);
            h = __float2half_rn(v - __half2float(hv));   // lo residual
        } else {
            h = __float2half_rn(v);
        }
        int k = r >> 7, ncol = r & 127;
        int c = ncol >> 4, nl = ncol & 15;
        int s = k >> 5, quad = (k >> 3) & 3, j = k & 7;
        int di = ((c * 4 + s) * 64 + quad * 16 + nl) * 8 + j;
        wfrag[(size_t)w * 16384 + di] = h;
        return;
    }
    __shared__ int h[256];
    h[tid] = 0;
    __syncthreads();
    int base = blockIdx.x * 2048 + tid * 8;
    if (base + 7 < E) {
        int4 d0 = *(const int4*)&dst[base];
        int4 d1 = *(const int4*)&dst[base + 4];
        atomicAdd(&h[d0.x >> 8], 1);
        atomicAdd(&h[d0.y >> 8], 1);
        atomicAdd(&h[d0.z >> 8], 1);
        atomicAdd(&h[d0.w >> 8], 1);
        atomicAdd(&h[d1.x >> 8], 1);
        atomicAdd(&h[d1.y >> 8], 1);
        atomicAdd(&h[d1.z >> 8], 1);
        atomicAdd(&h[d1.w >> 8], 1);
    } else {
        for (int e = base; e < E; ++e) atomicAdd(&h[dst[e] >> 8], 1);
    }
    __syncthreads();
    histT[tid * 400 + blockIdx.x] = h[tid];
}

// ---------------- K_B: per-bin exclusive scan over blocks (256 parallel blocks) --------------
__global__ __launch_bounds__(512) void scan_bins(int* __restrict__ histT,
                                                 int* __restrict__ totals, int nb) {
    __shared__ int s[512];
    int b = blockIdx.x;
    int t = threadIdx.x;
    int v = (t < nb) ? histT[b * 400 + t] : 0;
    s[t] = v;
    __syncthreads();
    for (int off = 1; off < 512; off <<= 1) {
        int x = (t >= off) ? s[t - off] : 0;
        __syncthreads();
        s[t] += x;
        __syncthreads();
    }
    if (t < nb) histT[b * 400 + t] = s[t] - v;   // exclusive within bin
    if (t == 511) totals[b] = s[511];
}

// ---------------- K_C: exclusive scan of 256 bin totals -> binbase[257] ----------------------
__global__ __launch_bounds__(256) void scan_totals(const int* __restrict__ totals,
                                                   int* __restrict__ binbase) {
    __shared__ int s[256];
    int t = threadIdx.x;
    int v = totals[t];
    s[t] = v;
    __syncthreads();
    for (int off = 1; off < 256; off <<= 1) {
        int x = (t >= off) ? s[t - off] : 0;
        __syncthreads();
        s[t] += x;
        __syncthreads();
    }
    binbase[t] = s[t] - v;
    if (t == 255) binbase[256] = s[255];
}

// ---------------- K_D: bucket scatter (LDS atomics only) + layer-1 MFMA GEMM (fused) ---------
__global__ __launch_bounds__(256) void scat_gemm1(const int* __restrict__ src,
                                                  const int* __restrict__ dst,
                                                  const int* __restrict__ histT,
                                                  const int* __restrict__ binbase,
                                                  int* __restrict__ pairS, int E,
                                                  int scatBlocks,
                                                  const float* __restrict__ X,
                                                  const __half* __restrict__ wfrag,
                                                  __half* __restrict__ H, int Nrows) {
    int tid = threadIdx.x;
    if (blockIdx.x < scatBlocks) {
        __shared__ int pos[256];
        pos[tid] = binbase[tid] + histT[tid * 400 + blockIdx.x];
        __syncthreads();
        int base = blockIdx.x * 2048 + tid * 8;
        if (base + 7 < E) {
            int4 d0 = *(const int4*)&dst[base];
            int4 d1 = *(const int4*)&dst[base + 4];
            int4 s0 = *(const int4*)&src[base];
            int4 s1 = *(const int4*)&src[base + 4];
            int p0 = atomicAdd(&pos[d0.x >> 8], 1);
            int p1 = atomicAdd(&pos[d0.y >> 8], 1);
            int p2 = atomicAdd(&pos[d0.z >> 8], 1);
            int p3 = atomicAdd(&pos[d0.w >> 8], 1);
            int p4 = atomicAdd(&pos[d1.x >> 8], 1);
            int p5 = atomicAdd(&pos[d1.y >> 8], 1);
            int p6 = atomicAdd(&pos[d1.z >> 8], 1);
            int p7 = atomicAdd(&pos[d1.w >> 8], 1);
            pairS[p0] = ((d0.x & 255) << 16) | s0.x;
            pairS[p1] = ((d0.y & 255) << 16) | s0.y;
            pairS[p2] = ((d0.z & 255) << 16) | s0.z;
            pairS[p3] = ((d0.w & 255) << 16) | s0.w;
            pairS[p4] = ((d1.x & 255) << 16) | s1.x;
            pairS[p5] = ((d1.y & 255) << 16) | s1.y;
            pairS[p6] = ((d1.z & 255) << 16) | s1.z;
            pairS[p7] = ((d1.w & 255) << 16) | s1.w;
        } else {
            for (int e = base; e < E; ++e) {
                int d = dst[e];
                int p = atomicAdd(&pos[d >> 8], 1);
                pairS[p] = ((d & 255) << 16) | src[e];
            }
        }
        return;
    }
    int rowbase = (blockIdx.x - scatBlocks) * 64;
    int l = tid & 63;
    int wid = tid >> 6;
    int rb = wid * 16;
    int quad = l >> 4;
    int nn = l & 15;
    int gr = rowbase + rb + nn;
    v8h ah[4], al[4];
    if (gr < Nrows) {
        const float* Xr = &X[(size_t)gr * 128 + quad * 8];
#pragma unroll
        for (int k = 0; k < 4; ++k) {
            float4 f0 = *(const float4*)&Xr[k * 32];
            float4 f1 = *(const float4*)&Xr[k * 32 + 4];
            float ff[8] = {f0.x, f0.y, f0.z, f0.w, f1.x, f1.y, f1.z, f1.w};
            v8h h, lo;
#pragma unroll
            for (int m = 0; m < 8; ++m) {
                _Float16 hv = (_Float16)ff[m];
                h[m] = hv;
                lo[m] = (_Float16)(ff[m] - (float)hv);
            }
            ah[k] = h;
            al[k] = lo;
        }
    } else {
#pragma unroll
        for (int k = 0; k < 4; ++k) {
            v8h z;
#pragma unroll
            for (int m = 0; m < 8; ++m) z[m] = (_Float16)0.f;
            ah[k] = z;
            al[k] = z;
        }
    }
    const v8h* Wh = (const v8h*)wfrag;             // section 0: W1hi
    const v8h* Wl = (const v8h*)(wfrag + 16384);   // section 1: W1lo
    v4f acc[8] = {};
    v8h bh0 = Wh[0 * 64 + l];
    v8h bh1 = Wh[1 * 64 + l];
    v8h bh2 = Wh[2 * 64 + l];
    v8h bh3 = Wh[3 * 64 + l];
#pragma unroll
    for (int c = 0; c < 8; ++c) {
        v8h bl0 = Wl[(c * 4 + 0) * 64 + l];
        v8h bl1 = Wl[(c * 4 + 1) * 64 + l];
        v8h bl2 = Wl[(c * 4 + 2) * 64 + l];
        v8h bl3 = Wl[(c * 4 + 3) * 64 + l];
        acc[c] = __builtin_amdgcn_mfma_f32_16x16x32_f16(ah[0], bh0, acc[c], 0, 0, 0);
        acc[c] = __builtin_amdgcn_mfma_f32_16x16x32_f16(ah[1], bh1, acc[c], 0, 0, 0);
        acc[c] = __builtin_amdgcn_mfma_f32_16x16x32_f16(ah[2], bh2, acc[c], 0, 0, 0);
        acc[c] = __builtin_amdgcn_mfma_f32_16x16x32_f16(ah[3], bh3, acc[c], 0, 0, 0);
        acc[c] = __builtin_amdgcn_mfma_f32_16x16x32_f16(al[0], bh0, acc[c], 0, 0, 0);
        acc[c] = __builtin_amdgcn_mfma_f32_16x16x32_f16(al[1], bh1, acc[c], 0, 0, 0);
        acc[c] = __builtin_amdgcn_mfma_f32_16x16x32_f16(al[2], bh2, acc[c], 0, 0, 0);
        acc[c] = __builtin_amdgcn_mfma_f32_16x16x32_f16(al[3], bh3, acc[c], 0, 0, 0);
        v8h nh0, nh1, nh2, nh3;
        if (c < 7) {
            nh0 = Wh[((c + 1) * 4 + 0) * 64 + l];
            nh1 = Wh[((c + 1) * 4 + 1) * 64 + l];
            nh2 = Wh[((c + 1) * 4 + 2) * 64 + l];
            nh3 = Wh[((c + 1) * 4 + 3) * 64 + l];
        }
        acc[c] = __builtin_amdgcn_mfma_f32_16x16x32_f16(ah[0], bl0, acc[c], 0, 0, 0);
        acc[c] = __builtin_amdgcn_mfma_f32_16x16x32_f16(ah[1], bl1, acc[c], 0, 0, 0);
        acc[c] = __builtin_amdgcn_mfma_f32_16x16x32_f16(ah[2], bl2, acc[c], 0, 0, 0);
        acc[c] = __builtin_amdgcn_mfma_f32_16x16x32_f16(ah[3], bl3, acc[c], 0, 0, 0);
        if (c < 7) { bh0 = nh0; bh1 = nh1; bh2 = nh2; bh3 = nh3; }
    }
#pragma unroll
    for (int reg = 0; reg < 4; ++reg) {
        int grr = rowbase + rb + quad * 4 + reg;
        if (grr < Nrows) {
#pragma unroll
            for (int c = 0; c < 8; ++c)
                H[(size_t)grr * 128 + c * 16 + nn] = __float2half_rn(acc[c][reg]);
        }
    }
}

// ---------------- K_E: per-bucket CSR finalize (rowptr/dinv/self-loops/col), LDS only --------
__global__ __launch_bounds__(256) void bucket_csr(const int* __restrict__ pairS,
                                                  const int* __restrict__ binbase,
                                                  int* __restrict__ rowptr,
                                                  float* __restrict__ dinv,
                                                  int* __restrict__ col, int N) {
    __shared__ int h[256];
    __shared__ int sc[256];
    __shared__ int cnt2[256];
    int b = blockIdx.x;
    int t = threadIdx.x;
    int ebeg = binbase[b], eend = binbase[b + 1];
    int base_sl = ebeg + b * 256;       // edges + self-loops before this bucket
    h[t] = 0;
    __syncthreads();
    for (int i = ebeg + t; i < eend; i += 256) atomicAdd(&h[pairS[i] >> 16], 1);
    __syncthreads();
    int deg = h[t];
    int node = b * 256 + t;
    bool valid = node < N;
    int v = valid ? (deg + 1) : 0;
    sc[t] = v;
    __syncthreads();
    for (int off = 1; off < 256; off <<= 1) {
        int x = (t >= off) ? sc[t - off] : 0;
        __syncthreads();
        sc[t] += x;
        __syncthreads();
    }
    int rs = base_sl + sc[t] - v;       // row start (self-loop slot)
    if (valid) {
        rowptr[node + 1] = base_sl + sc[t];
        dinv[node] = rsqrtf((float)(deg + 1));
        col[rs] = node;                 // self-loop first
        if (node == 0) rowptr[0] = 0;
    }
    cnt2[t] = rs + 1;                   // next free edge slot
    __syncthreads();
    for (int i = ebeg + t; i < eend; i += 256) {
        int pv = pairS[i];
        int p = atomicAdd(&cnt2[pv >> 16], 1);
        col[p] = pv & 0xFFFF;
    }
}

// ---------------- layer-1 QUARTER-SWEEP agg: x̃1 = dinv⊙relu(dinv_n·Σ dinv_s·H[s] + b) -------
// Block = 64 nodes, 4 lanes/node (one 64B cacheline slice).  Dim split into 4 quarters:
// per-quarter working set = N*64B = 3.2MB < 4MB/XCD L2 -> re-reads are L2 hits.
// Grid 782 fully resident -> all blocks sweep q in lockstep.
__global__ __launch_bounds__(256, 8) void agg_h(const __half* __restrict__ H,
                                                const float* __restrict__ dinv,
                                                const int* __restrict__ rowptr,
                                                const int* __restrict__ col,
                                                const float* __restrict__ bias,
                                                __half* __restrict__ out, int n) {
    int grp = threadIdx.x >> 2;          // node within block, 0..63
    int lane = threadIdx.x & 3;          // 16B slice within the 64B quarter
    int node = blockIdx.x * 64 + grp;
    int beg = 0, end = 0;
    float dn = 0.f;
    if (node < n) { beg = rowptr[node]; end = rowptr[node + 1]; dn = dinv[node]; }
    auto pk = [](float x, float y) { __half2 h = __floats2half2_rn(x, y); return *(unsigned int*)&h; };
    for (int q = 0; q < 4; ++q) {
        int t = q * 32 + lane * 8;       // half offset within row
        float a[8] = {};
        int k = beg;
        for (; k + 4 <= end; k += 4) {
            int s0 = col[k], s1 = col[k + 1], s2 = col[k + 2], s3 = col[k + 3];
            float w0 = dinv[s0], w1 = dinv[s1], w2 = dinv[s2], w3 = dinv[s3];
            uint4 r0 = *(const uint4*)&H[(size_t)s0 * 128 + t];
            uint4 r1 = *(const uint4*)&H[(size_t)s1 * 128 + t];
            uint4 r2 = *(const uint4*)&H[(size_t)s2 * 128 + t];
            uint4 r3 = *(const uint4*)&H[(size_t)s3 * 128 + t];
            const __half2* h0 = (const __half2*)&r0;
            const __half2* h1 = (const __half2*)&r1;
            const __half2* h2 = (const __half2*)&r2;
            const __half2* h3 = (const __half2*)&r3;
#pragma unroll
            for (int m = 0; m < 4; ++m) {
                float2 f0 = __half22float2(h0[m]);
                float2 f1 = __half22float2(h1[m]);
                float2 f2 = __half22float2(h2[m]);
                float2 f3 = __half22float2(h3[m]);
                a[2 * m]     += f0.x * w0 + f1.x * w1 + f2.x * w2 + f3.x * w3;
                a[2 * m + 1] += f0.y * w0 + f1.y * w1 + f2.y * w2 + f3.y * w3;
            }
        }
        for (; k < end; ++k) {
            int s0 = col[k];
            float w0 = dinv[s0];
            uint4 r0 = *(const uint4*)&H[(size_t)s0 * 128 + t];
            const __half2* h0 = (const __half2*)&r0;
#pragma unroll
            for (int m = 0; m < 4; ++m) {
                float2 f0 = __half22float2(h0[m]);
                a[2 * m] += f0.x * w0;
                a[2 * m + 1] += f0.y * w0;
            }
        }
        if (node < n) {
            float4 b0 = *(const float4*)&bias[t];
            float4 b1 = *(const float4*)&bias[t + 4];
            float r0 = fmaxf(a[0] * dn + b0.x, 0.f) * dn;
            float r1 = fmaxf(a[1] * dn + b0.y, 0.f) * dn;
            float r2 = fmaxf(a[2] * dn + b0.z, 0.f) * dn;
            float r3 = fmaxf(a[3] * dn + b0.w, 0.f) * dn;
            float r4 = fmaxf(a[4] * dn + b1.x, 0.f) * dn;
            float r5 = fmaxf(a[5] * dn + b1.y, 0.f) * dn;
            float r6 = fmaxf(a[6] * dn + b1.z, 0.f) * dn;
            float r7 = fmaxf(a[7] * dn + b1.w, 0.f) * dn;
            uint4 o = make_uint4(pk(r0, r1), pk(r2, r3), pk(r4, r5), pk(r6, r7));
            *(uint4*)&out[(size_t)node * 128 + t] = o;
        }
    }
}

// ---------------- FUSED layer (2,3) QUARTER-SWEEP: Out = post( (dinv ⊙ Â·Xs) @ W + b ) ------
// Phase A: 64 nodes x 4 lanes, q=0..3 sweep (same L2-residency argument), y in LDS.
// Phase B: 4 waves x 16 rows x 128 cols, mfma_f32_16x16x32_f16 vs pre-swizzled wfrag.
__global__ __launch_bounds__(256, 8) void agg_gemm(const __half* __restrict__ Xs,
                                                   const float* __restrict__ dinv,
                                                   const int* __restrict__ rowptr,
                                                   const int* __restrict__ col,
                                                   const __half* __restrict__ wfrag,
                                                   const float* __restrict__ bias,
                                                   __half* __restrict__ Out,
                                                   int n, int finalLayer) {
    __shared__ __align__(16) _Float16 y[64][136];   // +8 halfs pad
    int tid = threadIdx.x;
    int rowbase = blockIdx.x * 64;
    // ---- phase A: quarter sweep ----
    {
        int grp = tid >> 2;
        int lane = tid & 3;
        int node = rowbase + grp;
        int beg = 0, end = 0;
        float dn = 0.f;
        if (node < n) { beg = rowptr[node]; end = rowptr[node + 1]; dn = dinv[node]; }
        for (int q = 0; q < 4; ++q) {
            int t = q * 32 + lane * 8;
            float a[8] = {};
            int k = beg;
            for (; k + 4 <= end; k += 4) {
                int s0 = col[k], s1 = col[k + 1], s2 = col[k + 2], s3 = col[k + 3];
                uint4 r0 = *(const uint4*)&Xs[(size_t)s0 * 128 + t];
                uint4 r1 = *(const uint4*)&Xs[(size_t)s1 * 128 + t];
                uint4 r2 = *(const uint4*)&Xs[(size_t)s2 * 128 + t];
                uint4 r3 = *(const uint4*)&Xs[(size_t)s3 * 128 + t];
                const __half2* h0 = (const __half2*)&r0;
                const __half2* h1 = (const __half2*)&r1;
                const __half2* h2 = (const __half2*)&r2;
                const __half2* h3 = (const __half2*)&r3;
#pragma unroll
                for (int m = 0; m < 4; ++m) {
                    float2 f0 = __half22float2(h0[m]);
                    float2 f1 = __half22float2(h1[m]);
                    float2 f2 = __half22float2(h2[m]);
                    float2 f3 = __half22float2(h3[m]);
                    a[2 * m]     += (f0.x + f1.x) + (f2.x + f3.x);
                    a[2 * m + 1] += (f0.y + f1.y) + (f2.y + f3.y);
                }
            }
            for (; k < end; ++k) {
                uint4 r0 = *(const uint4*)&Xs[(size_t)col[k] * 128 + t];
                const __half2* h0 = (const __half2*)&r0;
#pragma unroll
                for (int m = 0; m < 4; ++m) {
                    float2 f0 = __half22float2(h0[m]);
                    a[2 * m] += f0.x;
                    a[2 * m + 1] += f0.y;
                }
            }
            v8h yv;
#pragma unroll
            for (int m = 0; m < 8; ++m) yv[m] = (_Float16)(a[m] * dn);
            *(v8h*)&y[grp][t] = yv;
        }
    }
    __syncthreads();
    // ---- phase B: 4 waves x 16 rows x 128 cols ----
    int l = tid & 63;
    int wid = tid >> 6;
    int rb = wid * 16;
    int quad = l >> 4;
    int nn = l & 15;
    v8h a0 = *(const v8h*)&y[rb + nn][0 * 32 + quad * 8];
    v8h a1 = *(const v8h*)&y[rb + nn][1 * 32 + quad * 8];
    v8h a2 = *(const v8h*)&y[rb + nn][2 * 32 + quad * 8];
    v8h a3 = *(const v8h*)&y[rb + nn][3 * 32 + quad * 8];
    const v8h* Wf = (const v8h*)wfrag;
    v4f acc[8] = {};
#pragma unroll
    for (int c = 0; c < 8; ++c) {
        v8h b0 = Wf[(c * 4 + 0) * 64 + l];
        v8h b1 = Wf[(c * 4 + 1) * 64 + l];
        v8h b2 = Wf[(c * 4 + 2) * 64 + l];
        v8h b3 = Wf[(c * 4 + 3) * 64 + l];
        acc[c] = __builtin_amdgcn_mfma_f32_16x16x32_f16(a0, b0, acc[c], 0, 0, 0);
        acc[c] = __builtin_amdgcn_mfma_f32_16x16x32_f16(a1, b1, acc[c], 0, 0, 0);
        acc[c] = __builtin_amdgcn_mfma_f32_16x16x32_f16(a2, b2, acc[c], 0, 0, 0);
        acc[c] = __builtin_amdgcn_mfma_f32_16x16x32_f16(a3, b3, acc[c], 0, 0, 0);
    }
#pragma unroll
    for (int reg = 0; reg < 4; ++reg) {
        int gr = rowbase + rb + quad * 4 + reg;
        if (gr < n) {
            float dn = dinv[gr];
#pragma unroll
            for (int c = 0; c < 8; ++c) {
                float z = acc[c][reg] + bias[c * 16 + nn];
                if (!finalLayer) z = fmaxf(z, 0.f) * dn;
                Out[(size_t)gr * 128 + c * 16 + nn] = __float2half_rn(z);
            }
        }
    }
}

// ---------------- edge decoder over fp16 X ----------------
__global__ __launch_bounds__(256) void decoder_h(const __half* __restrict__ X,
                                                 const int* __restrict__ eli,
                                                 float* __restrict__ out, int EL) {
    int e = blockIdx.x * 16 + (threadIdx.x >> 4);
    int lane = threadIdx.x & 15;
    if (e >= EL) return;
    int u = eli[e], v = eli[EL + e];
    uint4 ra = *(const uint4*)&X[(size_t)u * 128 + lane * 8];
    uint4 rb = *(const uint4*)&X[(size_t)v * 128 + lane * 8];
    const __half2* ha = (const __half2*)&ra;
    const __half2* hb = (const __half2*)&rb;
    float d = 0.f;
#pragma unroll
    for (int j = 0; j < 4; ++j) {
        float2 fa = __half22float2(ha[j]);
        float2 fb = __half22float2(hb[j]);
        d += fa.x * fb.x + fa.y * fb.y;
    }
#pragma unroll
    for (int off = 8; off > 0; off >>= 1) d += __shfl_xor(d, off);
    if (lane == 0) out[e] = d;
}

extern "C" void kernel_launch(void* const* d_in, const int* in_sizes, int n_in,
                              void* d_out, int out_size, void* d_ws, size_t ws_size,
                              hipStream_t stream) {
    const float* x0 = (const float*)d_in[0];
    const float* W1 = (const float*)d_in[1];
    const float* b1 = (const float*)d_in[2];
    const float* W2 = (const float*)d_in[3];
    const float* b2 = (const float*)d_in[4];
    const float* W3 = (const float*)d_in[5];
    const float* b3 = (const float*)d_in[6];
    const int* ei   = (const int*)d_in[7];
    const int* eli  = (const int*)d_in[8];
    float* out = (float*)d_out;

    const int D = 128;
    const int N  = in_sizes[0] / D;
    const int E  = in_sizes[7] / 2;
    const int EL = in_sizes[8] / 2;

    const int* src = ei;
    const int* dst = ei + E;

    // -------- workspace carve-up (256B aligned) --------
    char* ws = (char*)d_ws;
    size_t off = 0;
    auto alloc = [&](size_t bytes) -> void* {
        off = (off + 255) & ~(size_t)255;
        void* p = ws + off;
        off += bytes;
        return p;
    };
    int*    histT   = (int*)alloc((size_t)256 * 400 * sizeof(int));  // [bin][block]
    int*    totals  = (int*)alloc(256 * sizeof(int));
    int*    binbase = (int*)alloc(257 * sizeof(int));
    int*    pairS   = (int*)alloc((size_t)E * sizeof(int));          // (dst&255)<<16 | src
    int*    rowptr  = (int*)alloc((size_t)(N + 1) * sizeof(int));
    float*  dinv    = (float*)alloc((size_t)N * sizeof(float));
    int*    col     = (int*)alloc((size_t)(E + N) * sizeof(int));
    __half* wfrag   = (__half*)alloc((size_t)4 * 16384 * sizeof(__half));
    __half* hbuf    = (__half*)alloc((size_t)N * D * sizeof(__half));  // h1 / x̃2
    __half* xbuf    = (__half*)alloc((size_t)N * D * sizeof(__half));  // x̃1 / x3
    (void)ws_size;

    int histBlocks = (E + 2047) / 2048;         // 391 (<=400, <=512 for scan)
    int gemmGrid = (N + 63) / 64;
    int aggGrid  = (N + 63) / 64;               // 64-node agg blocks, fully resident
    int nbkt = (N + 255) / 256;                 // 196

    // ---- K_A: dst-bucket histogram + W swizzle ----
    hist_wswz<<<histBlocks + 256, 256, 0, stream>>>(dst, histT, E, histBlocks,
                                                    W1, W2, W3, wfrag);
    // ---- K_B/K_C: scans ----
    scan_bins<<<256, 512, 0, stream>>>(histT, totals, histBlocks);
    scan_totals<<<1, 256, 0, stream>>>(totals, binbase);
    // ---- K_D: bucket scatter (LDS atomics) + layer-1 MFMA GEMM ----
    scat_gemm1<<<histBlocks + gemmGrid, 256, 0, stream>>>(src, dst, histT, binbase,
                                                          pairS, E, histBlocks,
                                                          x0, wfrag, hbuf, N);
    // ---- K_E: per-bucket CSR finalize ----
    bucket_csr<<<nbkt, 256, 0, stream>>>(pairS, binbase, rowptr, dinv, col, N);

    // ---- layer 1: quarter-sweep agg over unscaled h1, emits prescaled x̃1 ----
    agg_h<<<aggGrid, 256, 0, stream>>>(hbuf, dinv, rowptr, col, b1, xbuf, N);
    // ---- layer 2: quarter-sweep agg + MFMA, emits prescaled x̃2 ----
    agg_gemm<<<aggGrid, 256, 0, stream>>>(xbuf, dinv, rowptr, col, wfrag + 2 * 16384, b2, hbuf, N, 0);
    // ---- layer 3: quarter-sweep agg + MFMA, emits final x3 ----
    agg_gemm<<<aggGrid, 256, 0, stream>>>(hbuf, dinv, rowptr, col, wfrag + 3 * 16384, b3, xbuf, N, 1);

    // ---- decoder ----
    decoder_h<<<(EL + 15) / 16, 256, 0, stream>>>(xbuf, eli, out, EL);
}

// Round 13
// 230.948 us; speedup vs baseline: 1.2450x; 1.2450x over previous
//
#include <hip/hip_runtime.h>
#include <hip/hip_bf16.h>
#include <hip/hip_fp16.h>

typedef _Float16 v8h __attribute__((ext_vector_type(8)));
typedef float v4f __attribute__((ext_vector_type(4)));

// ---------------- K_A: per-block dst-bucket histogram (LDS) + W-swizzle (fused) ----------------
// Blocks [0,histBlocks): LDS hist of dst>>8 over 2048 edges -> histT[bin][block].
// Blocks [histBlocks, +256): pack W1hi/W1lo/W2/W3 into fp16 MFMA B-fragment order.
__global__ __launch_bounds__(256) void hist_wswz(const int* __restrict__ dst,
                                                 int* __restrict__ histT, int E,
                                                 int histBlocks,
                                                 const float* __restrict__ W1,
                                                 const float* __restrict__ W2,
                                                 const float* __restrict__ W3,
                                                 __half* __restrict__ wfrag) {
    int tid = threadIdx.x;
    if (blockIdx.x >= histBlocks) {
        int o = (blockIdx.x - histBlocks) * 256 + tid;
        int w = o >> 14, r = o & 16383;
        const float* Ws = (w >= 3) ? W3 : ((w == 2) ? W2 : W1);
        float v = Ws[r];
        __half h;
        if (w == 1) {
            __half hv = __float2half_rn(v);
            h = __float2half_rn(v - __half2float(hv));   // lo residual
        } else {
            h = __float2half_rn(v);
        }
        int k = r >> 7, ncol = r & 127;
        int c = ncol >> 4, nl = ncol & 15;
        int s = k >> 5, quad = (k >> 3) & 3, j = k & 7;
        int di = ((c * 4 + s) * 64 + quad * 16 + nl) * 8 + j;
        wfrag[(size_t)w * 16384 + di] = h;
        return;
    }
    __shared__ int h[256];
    h[tid] = 0;
    __syncthreads();
    int base = blockIdx.x * 2048 + tid * 8;
    if (base + 7 < E) {
        int4 d0 = *(const int4*)&dst[base];
        int4 d1 = *(const int4*)&dst[base + 4];
        atomicAdd(&h[d0.x >> 8], 1);
        atomicAdd(&h[d0.y >> 8], 1);
        atomicAdd(&h[d0.z >> 8], 1);
        atomicAdd(&h[d0.w >> 8], 1);
        atomicAdd(&h[d1.x >> 8], 1);
        atomicAdd(&h[d1.y >> 8], 1);
        atomicAdd(&h[d1.z >> 8], 1);
        atomicAdd(&h[d1.w >> 8], 1);
    } else {
        for (int e = base; e < E; ++e) atomicAdd(&h[dst[e] >> 8], 1);
    }
    __syncthreads();
    histT[tid * 400 + blockIdx.x] = h[tid];
}

// ---------------- K_B: per-bin exclusive scan over blocks (256 parallel blocks) --------------
__global__ __launch_bounds__(512) void scan_bins(int* __restrict__ histT,
                                                 int* __restrict__ totals, int nb) {
    __shared__ int s[512];
    int b = blockIdx.x;
    int t = threadIdx.x;
    int v = (t < nb) ? histT[b * 400 + t] : 0;
    s[t] = v;
    __syncthreads();
    for (int off = 1; off < 512; off <<= 1) {
        int x = (t >= off) ? s[t - off] : 0;
        __syncthreads();
        s[t] += x;
        __syncthreads();
    }
    if (t < nb) histT[b * 400 + t] = s[t] - v;   // exclusive within bin
    if (t == 511) totals[b] = s[511];
}

// ---------------- K_C: exclusive scan of 256 bin totals -> binbase[257] ----------------------
__global__ __launch_bounds__(256) void scan_totals(const int* __restrict__ totals,
                                                   int* __restrict__ binbase) {
    __shared__ int s[256];
    int t = threadIdx.x;
    int v = totals[t];
    s[t] = v;
    __syncthreads();
    for (int off = 1; off < 256; off <<= 1) {
        int x = (t >= off) ? s[t - off] : 0;
        __syncthreads();
        s[t] += x;
        __syncthreads();
    }
    binbase[t] = s[t] - v;
    if (t == 255) binbase[256] = s[255];
}

// ---------------- K_D: bucket scatter (LDS atomics only) + layer-1 MFMA GEMM (fused) ---------
// Scatter blocks [0,scatBlocks): pairS[pos] = ((dst&255)<<16)|src, pos from LDS counters
//   seeded with binbase+histT (no global atomics).  Requires src < 65536.
// Gemm blocks: H = X @ W1 via 3-term hi/lo fp16 split, zero LDS, pipelined B loads.
__global__ __launch_bounds__(256) void scat_gemm1(const int* __restrict__ src,
                                                  const int* __restrict__ dst,
                                                  const int* __restrict__ histT,
                                                  const int* __restrict__ binbase,
                                                  int* __restrict__ pairS, int E,
                                                  int scatBlocks,
                                                  const float* __restrict__ X,
                                                  const __half* __restrict__ wfrag,
                                                  __half* __restrict__ H, int Nrows) {
    int tid = threadIdx.x;
    if (blockIdx.x < scatBlocks) {
        __shared__ int pos[256];
        pos[tid] = binbase[tid] + histT[tid * 400 + blockIdx.x];
        __syncthreads();
        int base = blockIdx.x * 2048 + tid * 8;
        if (base + 7 < E) {
            int4 d0 = *(const int4*)&dst[base];
            int4 d1 = *(const int4*)&dst[base + 4];
            int4 s0 = *(const int4*)&src[base];
            int4 s1 = *(const int4*)&src[base + 4];
            int p0 = atomicAdd(&pos[d0.x >> 8], 1);
            int p1 = atomicAdd(&pos[d0.y >> 8], 1);
            int p2 = atomicAdd(&pos[d0.z >> 8], 1);
            int p3 = atomicAdd(&pos[d0.w >> 8], 1);
            int p4 = atomicAdd(&pos[d1.x >> 8], 1);
            int p5 = atomicAdd(&pos[d1.y >> 8], 1);
            int p6 = atomicAdd(&pos[d1.z >> 8], 1);
            int p7 = atomicAdd(&pos[d1.w >> 8], 1);
            pairS[p0] = ((d0.x & 255) << 16) | s0.x;
            pairS[p1] = ((d0.y & 255) << 16) | s0.y;
            pairS[p2] = ((d0.z & 255) << 16) | s0.z;
            pairS[p3] = ((d0.w & 255) << 16) | s0.w;
            pairS[p4] = ((d1.x & 255) << 16) | s1.x;
            pairS[p5] = ((d1.y & 255) << 16) | s1.y;
            pairS[p6] = ((d1.z & 255) << 16) | s1.z;
            pairS[p7] = ((d1.w & 255) << 16) | s1.w;
        } else {
            for (int e = base; e < E; ++e) {
                int d = dst[e];
                int p = atomicAdd(&pos[d >> 8], 1);
                pairS[p] = ((d & 255) << 16) | src[e];
            }
        }
        return;
    }
    int rowbase = (blockIdx.x - scatBlocks) * 64;
    int l = tid & 63;
    int wid = tid >> 6;
    int rb = wid * 16;
    int quad = l >> 4;
    int nn = l & 15;
    int gr = rowbase + rb + nn;
    v8h ah[4], al[4];
    if (gr < Nrows) {
        const float* Xr = &X[(size_t)gr * 128 + quad * 8];
#pragma unroll
        for (int k = 0; k < 4; ++k) {
            float4 f0 = *(const float4*)&Xr[k * 32];
            float4 f1 = *(const float4*)&Xr[k * 32 + 4];
            float ff[8] = {f0.x, f0.y, f0.z, f0.w, f1.x, f1.y, f1.z, f1.w};
            v8h h, lo;
#pragma unroll
            for (int m = 0; m < 8; ++m) {
                _Float16 hv = (_Float16)ff[m];
                h[m] = hv;
                lo[m] = (_Float16)(ff[m] - (float)hv);
            }
            ah[k] = h;
            al[k] = lo;
        }
    } else {
#pragma unroll
        for (int k = 0; k < 4; ++k) {
            v8h z;
#pragma unroll
            for (int m = 0; m < 8; ++m) z[m] = (_Float16)0.f;
            ah[k] = z;
            al[k] = z;
        }
    }
    const v8h* Wh = (const v8h*)wfrag;             // section 0: W1hi
    const v8h* Wl = (const v8h*)(wfrag + 16384);   // section 1: W1lo
    v4f acc[8] = {};
    v8h bh0 = Wh[0 * 64 + l];
    v8h bh1 = Wh[1 * 64 + l];
    v8h bh2 = Wh[2 * 64 + l];
    v8h bh3 = Wh[3 * 64 + l];
#pragma unroll
    for (int c = 0; c < 8; ++c) {
        v8h bl0 = Wl[(c * 4 + 0) * 64 + l];
        v8h bl1 = Wl[(c * 4 + 1) * 64 + l];
        v8h bl2 = Wl[(c * 4 + 2) * 64 + l];
        v8h bl3 = Wl[(c * 4 + 3) * 64 + l];
        acc[c] = __builtin_amdgcn_mfma_f32_16x16x32_f16(ah[0], bh0, acc[c], 0, 0, 0);
        acc[c] = __builtin_amdgcn_mfma_f32_16x16x32_f16(ah[1], bh1, acc[c], 0, 0, 0);
        acc[c] = __builtin_amdgcn_mfma_f32_16x16x32_f16(ah[2], bh2, acc[c], 0, 0, 0);
        acc[c] = __builtin_amdgcn_mfma_f32_16x16x32_f16(ah[3], bh3, acc[c], 0, 0, 0);
        acc[c] = __builtin_amdgcn_mfma_f32_16x16x32_f16(al[0], bh0, acc[c], 0, 0, 0);
        acc[c] = __builtin_amdgcn_mfma_f32_16x16x32_f16(al[1], bh1, acc[c], 0, 0, 0);
        acc[c] = __builtin_amdgcn_mfma_f32_16x16x32_f16(al[2], bh2, acc[c], 0, 0, 0);
        acc[c] = __builtin_amdgcn_mfma_f32_16x16x32_f16(al[3], bh3, acc[c], 0, 0, 0);
        v8h nh0, nh1, nh2, nh3;
        if (c < 7) {
            nh0 = Wh[((c + 1) * 4 + 0) * 64 + l];
            nh1 = Wh[((c + 1) * 4 + 1) * 64 + l];
            nh2 = Wh[((c + 1) * 4 + 2) * 64 + l];
            nh3 = Wh[((c + 1) * 4 + 3) * 64 + l];
        }
        acc[c] = __builtin_amdgcn_mfma_f32_16x16x32_f16(ah[0], bl0, acc[c], 0, 0, 0);
        acc[c] = __builtin_amdgcn_mfma_f32_16x16x32_f16(ah[1], bl1, acc[c], 0, 0, 0);
        acc[c] = __builtin_amdgcn_mfma_f32_16x16x32_f16(ah[2], bl2, acc[c], 0, 0, 0);
        acc[c] = __builtin_amdgcn_mfma_f32_16x16x32_f16(ah[3], bl3, acc[c], 0, 0, 0);
        if (c < 7) { bh0 = nh0; bh1 = nh1; bh2 = nh2; bh3 = nh3; }
    }
#pragma unroll
    for (int reg = 0; reg < 4; ++reg) {
        int grr = rowbase + rb + quad * 4 + reg;
        if (grr < Nrows) {
#pragma unroll
            for (int c = 0; c < 8; ++c)
                H[(size_t)grr * 128 + c * 16 + nn] = __float2half_rn(acc[c][reg]);
        }
    }
}

// ---------------- K_E: per-bucket CSR finalize (rowptr/dinv/self-loops/col), LDS only --------
// Block b owns nodes [b*256, b*256+256) and edges [binbase[b], binbase[b+1]).
__global__ __launch_bounds__(256) void bucket_csr(const int* __restrict__ pairS,
                                                  const int* __restrict__ binbase,
                                                  int* __restrict__ rowptr,
                                                  float* __restrict__ dinv,
                                                  int* __restrict__ col, int N) {
    __shared__ int h[256];
    __shared__ int sc[256];
    __shared__ int cnt2[256];
    int b = blockIdx.x;
    int t = threadIdx.x;
    int ebeg = binbase[b], eend = binbase[b + 1];
    int base_sl = ebeg + b * 256;       // edges + self-loops before this bucket
    h[t] = 0;
    __syncthreads();
    for (int i = ebeg + t; i < eend; i += 256) atomicAdd(&h[pairS[i] >> 16], 1);
    __syncthreads();
    int deg = h[t];
    int node = b * 256 + t;
    bool valid = node < N;
    int v = valid ? (deg + 1) : 0;
    sc[t] = v;
    __syncthreads();
    for (int off = 1; off < 256; off <<= 1) {
        int x = (t >= off) ? sc[t - off] : 0;
        __syncthreads();
        sc[t] += x;
        __syncthreads();
    }
    int rs = base_sl + sc[t] - v;       // row start (self-loop slot)
    if (valid) {
        rowptr[node + 1] = base_sl + sc[t];
        dinv[node] = rsqrtf((float)(deg + 1));
        col[rs] = node;                 // self-loop first
        if (node == 0) rowptr[0] = 0;
    }
    cnt2[t] = rs + 1;                   // next free edge slot
    __syncthreads();
    for (int i = ebeg + t; i < eend; i += 256) {
        int pv = pairS[i];
        int p = atomicAdd(&cnt2[pv >> 16], 1);
        col[p] = pv & 0xFFFF;
    }
}

// ---------------- FUSED layer (2,3), 512 threads: Out = post( (dinv ⊙ Â·Xs) @ W + b ) -------
__global__ __launch_bounds__(512, 8) void agg_gemm(const __half* __restrict__ Xs,
                                                   const float* __restrict__ dinv,
                                                   const int* __restrict__ rowptr,
                                                   const int* __restrict__ col,
                                                   const __half* __restrict__ wfrag,
                                                   const float* __restrict__ bias,
                                                   __half* __restrict__ Out,
                                                   int n, int finalLayer) {
    __shared__ __align__(16) _Float16 y[64][136];   // +8 halfs pad
    int tid = threadIdx.x;
    int rowbase = blockIdx.x * 64;
    // ---- phase A ----
    {
        int grp = tid >> 4;               // 0..31
        int t = (tid & 15) * 8;           // dim offset (halfs)
        for (int g = 0; g < 2; ++g) {
            int rr = g * 32 + grp;
            int node = rowbase + rr;
            float a[8] = {};
            if (node < n) {
                int beg = rowptr[node], end = rowptr[node + 1];
                int k = beg;
                for (; k + 4 <= end; k += 4) {
                    int s0 = col[k], s1 = col[k + 1], s2 = col[k + 2], s3 = col[k + 3];
                    uint4 r0 = *(const uint4*)&Xs[(size_t)s0 * 128 + t];
                    uint4 r1 = *(const uint4*)&Xs[(size_t)s1 * 128 + t];
                    uint4 r2 = *(const uint4*)&Xs[(size_t)s2 * 128 + t];
                    uint4 r3 = *(const uint4*)&Xs[(size_t)s3 * 128 + t];
                    const __half2* h0 = (const __half2*)&r0;
                    const __half2* h1 = (const __half2*)&r1;
                    const __half2* h2 = (const __half2*)&r2;
                    const __half2* h3 = (const __half2*)&r3;
#pragma unroll
                    for (int m = 0; m < 4; ++m) {
                        float2 f0 = __half22float2(h0[m]);
                        float2 f1 = __half22float2(h1[m]);
                        float2 f2 = __half22float2(h2[m]);
                        float2 f3 = __half22float2(h3[m]);
                        a[2 * m]     += (f0.x + f1.x) + (f2.x + f3.x);
                        a[2 * m + 1] += (f0.y + f1.y) + (f2.y + f3.y);
                    }
                }
                for (; k < end; ++k) {
                    uint4 r0 = *(const uint4*)&Xs[(size_t)col[k] * 128 + t];
                    const __half2* h0 = (const __half2*)&r0;
#pragma unroll
                    for (int m = 0; m < 4; ++m) {
                        float2 f0 = __half22float2(h0[m]);
                        a[2 * m] += f0.x;
                        a[2 * m + 1] += f0.y;
                    }
                }
                float dn = dinv[node];
#pragma unroll
                for (int m = 0; m < 8; ++m) a[m] *= dn;
            }
            v8h yv;
#pragma unroll
            for (int m = 0; m < 8; ++m) yv[m] = (_Float16)a[m];
            *(v8h*)&y[rr][t] = yv;
        }
    }
    __syncthreads();
    // ---- phase B: 8 waves = 4 row-groups x 2 col-halves ----
    int l = tid & 63;
    int wid = tid >> 6;
    int rb = (wid >> 1) * 16;             // row-group
    int ch = wid & 1;                     // col-half
    int quad = l >> 4;
    int nn = l & 15;
    v8h a0 = *(const v8h*)&y[rb + nn][0 * 32 + quad * 8];
    v8h a1 = *(const v8h*)&y[rb + nn][1 * 32 + quad * 8];
    v8h a2 = *(const v8h*)&y[rb + nn][2 * 32 + quad * 8];
    v8h a3 = *(const v8h*)&y[rb + nn][3 * 32 + quad * 8];
    const v8h* Wf = (const v8h*)wfrag;
    v4f acc[4] = {};
#pragma unroll
    for (int c = 0; c < 4; ++c) {
        int cc = ch * 4 + c;
        v8h b0 = Wf[(cc * 4 + 0) * 64 + l];
        v8h b1 = Wf[(cc * 4 + 1) * 64 + l];
        v8h b2 = Wf[(cc * 4 + 2) * 64 + l];
        v8h b3 = Wf[(cc * 4 + 3) * 64 + l];
        acc[c] = __builtin_amdgcn_mfma_f32_16x16x32_f16(a0, b0, acc[c], 0, 0, 0);
        acc[c] = __builtin_amdgcn_mfma_f32_16x16x32_f16(a1, b1, acc[c], 0, 0, 0);
        acc[c] = __builtin_amdgcn_mfma_f32_16x16x32_f16(a2, b2, acc[c], 0, 0, 0);
        acc[c] = __builtin_amdgcn_mfma_f32_16x16x32_f16(a3, b3, acc[c], 0, 0, 0);
    }
#pragma unroll
    for (int reg = 0; reg < 4; ++reg) {
        int gr = rowbase + rb + quad * 4 + reg;
        if (gr < n) {
            float dn = dinv[gr];
#pragma unroll
            for (int c = 0; c < 4; ++c) {
                int cc = ch * 4 + c;
                float z = acc[c][reg] + bias[cc * 16 + nn];
                if (!finalLayer) z = fmaxf(z, 0.f) * dn;
                Out[(size_t)gr * 128 + cc * 16 + nn] = __float2half_rn(z);
            }
        }
    }
}

// ---------------- layer-1 aggregation: x̃1 = dinv ⊙ relu(dinv_n·Σ dinv_s·H1[s] + b) ----------------
__global__ __launch_bounds__(256, 8) void agg_h(const __half* __restrict__ H,
                                                const float* __restrict__ dinv,
                                                const int* __restrict__ rowptr,
                                                const int* __restrict__ col,
                                                const float* __restrict__ bias,
                                                __half* __restrict__ out, int n) {
    int node = blockIdx.x * 16 + (threadIdx.x >> 4);
    int t = (threadIdx.x & 15) * 8;
    if (node >= n) return;
    int beg = rowptr[node], end = rowptr[node + 1];
    float a[8] = {};
    int k = beg;
    for (; k + 4 <= end; k += 4) {
        int s0 = col[k], s1 = col[k + 1], s2 = col[k + 2], s3 = col[k + 3];
        float w0 = dinv[s0], w1 = dinv[s1], w2 = dinv[s2], w3 = dinv[s3];
        uint4 r0 = *(const uint4*)&H[(size_t)s0 * 128 + t];
        uint4 r1 = *(const uint4*)&H[(size_t)s1 * 128 + t];
        uint4 r2 = *(const uint4*)&H[(size_t)s2 * 128 + t];
        uint4 r3 = *(const uint4*)&H[(size_t)s3 * 128 + t];
        const __half2* h0 = (const __half2*)&r0;
        const __half2* h1 = (const __half2*)&r1;
        const __half2* h2 = (const __half2*)&r2;
        const __half2* h3 = (const __half2*)&r3;
#pragma unroll
        for (int m = 0; m < 4; ++m) {
            float2 f0 = __half22float2(h0[m]);
            float2 f1 = __half22float2(h1[m]);
            float2 f2 = __half22float2(h2[m]);
            float2 f3 = __half22float2(h3[m]);
            a[2 * m]     += f0.x * w0 + f1.x * w1 + f2.x * w2 + f3.x * w3;
            a[2 * m + 1] += f0.y * w0 + f1.y * w1 + f2.y * w2 + f3.y * w3;
        }
    }
    for (; k < end; ++k) {
        int s0 = col[k];
        float w0 = dinv[s0];
        uint4 r0 = *(const uint4*)&H[(size_t)s0 * 128 + t];
        const __half2* h0 = (const __half2*)&r0;
#pragma unroll
        for (int m = 0; m < 4; ++m) {
            float2 f0 = __half22float2(h0[m]);
            a[2 * m] += f0.x * w0;
            a[2 * m + 1] += f0.y * w0;
        }
    }
    float dn = dinv[node];
    float4 b0 = *(const float4*)&bias[t];
    float4 b1 = *(const float4*)&bias[t + 4];
    float r0 = fmaxf(a[0] * dn + b0.x, 0.f) * dn;
    float r1 = fmaxf(a[1] * dn + b0.y, 0.f) * dn;
    float r2 = fmaxf(a[2] * dn + b0.z, 0.f) * dn;
    float r3 = fmaxf(a[3] * dn + b0.w, 0.f) * dn;
    float r4 = fmaxf(a[4] * dn + b1.x, 0.f) * dn;
    float r5 = fmaxf(a[5] * dn + b1.y, 0.f) * dn;
    float r6 = fmaxf(a[6] * dn + b1.z, 0.f) * dn;
    float r7 = fmaxf(a[7] * dn + b1.w, 0.f) * dn;
    auto pk = [](float x, float y) { __half2 h = __floats2half2_rn(x, y); return *(unsigned int*)&h; };
    uint4 o = make_uint4(pk(r0, r1), pk(r2, r3), pk(r4, r5), pk(r6, r7));
    *(uint4*)&out[(size_t)node * 128 + t] = o;
}

// ---------------- edge decoder over fp16 X ----------------
__global__ __launch_bounds__(256) void decoder_h(const __half* __restrict__ X,
                                                 const int* __restrict__ eli,
                                                 float* __restrict__ out, int EL) {
    int e = blockIdx.x * 16 + (threadIdx.x >> 4);
    int lane = threadIdx.x & 15;
    if (e >= EL) return;
    int u = eli[e], v = eli[EL + e];
    uint4 ra = *(const uint4*)&X[(size_t)u * 128 + lane * 8];
    uint4 rb = *(const uint4*)&X[(size_t)v * 128 + lane * 8];
    const __half2* ha = (const __half2*)&ra;
    const __half2* hb = (const __half2*)&rb;
    float d = 0.f;
#pragma unroll
    for (int j = 0; j < 4; ++j) {
        float2 fa = __half22float2(ha[j]);
        float2 fb = __half22float2(hb[j]);
        d += fa.x * fb.x + fa.y * fb.y;
    }
#pragma unroll
    for (int off = 8; off > 0; off >>= 1) d += __shfl_xor(d, off);
    if (lane == 0) out[e] = d;
}

extern "C" void kernel_launch(void* const* d_in, const int* in_sizes, int n_in,
                              void* d_out, int out_size, void* d_ws, size_t ws_size,
                              hipStream_t stream) {
    const float* x0 = (const float*)d_in[0];
    const float* W1 = (const float*)d_in[1];
    const float* b1 = (const float*)d_in[2];
    const float* W2 = (const float*)d_in[3];
    const float* b2 = (const float*)d_in[4];
    const float* W3 = (const float*)d_in[5];
    const float* b3 = (const float*)d_in[6];
    const int* ei   = (const int*)d_in[7];
    const int* eli  = (const int*)d_in[8];
    float* out = (float*)d_out;

    const int D = 128;
    const int N  = in_sizes[0] / D;
    const int E  = in_sizes[7] / 2;
    const int EL = in_sizes[8] / 2;

    const int* src = ei;
    const int* dst = ei + E;

    // -------- workspace carve-up (256B aligned) --------
    char* ws = (char*)d_ws;
    size_t off = 0;
    auto alloc = [&](size_t bytes) -> void* {
        off = (off + 255) & ~(size_t)255;
        void* p = ws + off;
        off += bytes;
        return p;
    };
    int*    histT   = (int*)alloc((size_t)256 * 400 * sizeof(int));  // [bin][block]
    int*    totals  = (int*)alloc(256 * sizeof(int));
    int*    binbase = (int*)alloc(257 * sizeof(int));
    int*    pairS   = (int*)alloc((size_t)E * sizeof(int));          // (dst&255)<<16 | src
    int*    rowptr  = (int*)alloc((size_t)(N + 1) * sizeof(int));
    float*  dinv    = (float*)alloc((size_t)N * sizeof(float));
    int*    col     = (int*)alloc((size_t)(E + N) * sizeof(int));
    __half* wfrag   = (__half*)alloc((size_t)4 * 16384 * sizeof(__half));
    __half* hbuf    = (__half*)alloc((size_t)N * D * sizeof(__half));  // h1 / x̃2
    __half* xbuf    = (__half*)alloc((size_t)N * D * sizeof(__half));  // x̃1 / x3
    (void)ws_size;

    int histBlocks = (E + 2047) / 2048;         // 391 (<=400, <=512 for scan)
    int gemmGrid = (N + 63) / 64;
    int fusedGrid = (N + 63) / 64;
    int aggGrid  = (N + 15) / 16;
    int nbkt = (N + 255) / 256;                 // 196

    // ---- K_A: dst-bucket histogram + W swizzle ----
    hist_wswz<<<histBlocks + 256, 256, 0, stream>>>(dst, histT, E, histBlocks,
                                                    W1, W2, W3, wfrag);
    // ---- K_B/K_C: scans ----
    scan_bins<<<256, 512, 0, stream>>>(histT, totals, histBlocks);
    scan_totals<<<1, 256, 0, stream>>>(totals, binbase);
    // ---- K_D: bucket scatter (LDS atomics) + layer-1 MFMA GEMM ----
    scat_gemm1<<<histBlocks + gemmGrid, 256, 0, stream>>>(src, dst, histT, binbase,
                                                          pairS, E, histBlocks,
                                                          x0, wfrag, hbuf, N);
    // ---- K_E: per-bucket CSR finalize ----
    bucket_csr<<<nbkt, 256, 0, stream>>>(pairS, binbase, rowptr, dinv, col, N);

    // ---- layer 1: agg over unscaled h1, emits prescaled x̃1 ----
    agg_h<<<aggGrid, 256, 0, stream>>>(hbuf, dinv, rowptr, col, b1, xbuf, N);
    // ---- layer 2: fused 512-thread aggregate-first + MFMA, emits prescaled x̃2 ----
    agg_gemm<<<fusedGrid, 512, 0, stream>>>(xbuf, dinv, rowptr, col, wfrag + 2 * 16384, b2, hbuf, N, 0);
    // ---- layer 3: fused, emits final x3 ----
    agg_gemm<<<fusedGrid, 512, 0, stream>>>(hbuf, dinv, rowptr, col, wfrag + 3 * 16384, b3, xbuf, N, 1);

    // ---- decoder ----
    decoder_h<<<(EL + 15) / 16, 256, 0, stream>>>(xbuf, eli, out, EL);
}